// Round 11
// baseline (252.187 us; speedup 1.0000x reference)
//
#include <hip/hip_runtime.h>
#include <stdint.h>

typedef __attribute__((ext_vector_type(8))) short short8;
typedef __attribute__((ext_vector_type(4))) float f32x4;
typedef unsigned short u16;
typedef unsigned int u32;

#define NSIG   16
#define NPER   4096
#define DIN    256
#define DMODEL 1024
#define NB     16
#define NL     4096
#define LP1    4097
#define LDK32  40   // bf16 row stride: 80B rows -> 16B-aligned b128 reads

// ---------------------------------------------------------------------------
// Round-7 base (130 us, proven) with ONE change: all epilogue metadata
// (16 eidx + pos/sid/mod/role/pmask, packed to 32 VGPRs) is loaded BEFORE
// the k-loop, so its latency hides under the 8 GEMM iterations and the
// post-loop epilogue has no dependent-load chain ahead of the table gathers.
// Values/addresses identical to r7/r10.
// ---------------------------------------------------------------------------
__global__ __launch_bounds__(256, 4)
void enc_fused(const float* __restrict__ emb,     // [65536][256] f32
               const int* __restrict__ eidx,
               const int* __restrict__ pos,
               const int* __restrict__ sid,
               const int* __restrict__ mod_,
               const int* __restrict__ role,
               const unsigned char* __restrict__ pmask,
               const float* __restrict__ Wp,      // [16][1024][256] f32
               const float* __restrict__ bp,
               const float* __restrict__ cls,
               const float* __restrict__ pos_t,
               const float* __restrict__ id_t,
               const float* __restrict__ mod_t,
               const float* __restrict__ role_t,
               float* __restrict__ out)
{
    __shared__ u16 Ab[128 * LDK32];   // 10.0 KB
    __shared__ u16 Bb[128 * LDK32];   // 10.0 KB

    // XCD-chunked bijective swizzle (4096 % 8 == 0)
    const int bid = blockIdx.x;
    const int lg = (bid & 7) * 512 + (bid >> 3);
    const int rowBase = (lg >> 3) * 128;
    const int colBase = (lg & 7) * 128;
    const int s = rowBase >> 12;

    const int t = threadIdx.x;
    const int lane = t & 63;
    const int w = t >> 6;
    const int wr = w >> 1, wc = w & 1;
    const int l4 = lane >> 4;

    f32x4 acc[4][4] = {};

    // staging map: thread t -> rows r0+p*32, float col c4f (float4-wide)
    const int r0 = t >> 3;            // 0..31
    const int c4f = (t & 7) * 4;      // 0,4,..,28

    const float* Ag = emb + (size_t)rowBase * DIN;
    const float* Bg = Wp + ((size_t)s * DMODEL + colBase) * DIN;

    // ---- prologue: k-tile 0 into registers (issue FIRST: biggest stream) ----
    float4 rA[4], rB[4];
    #pragma unroll
    for (int p = 0; p < 4; ++p) {
        const int r = p * 32 + r0;
        rA[p] = *(const float4*)(Ag + (size_t)r * DIN + c4f);
        rB[p] = *(const float4*)(Bg + (size_t)r * DIN + c4f);
    }

    // ---- metadata prefetch (hidden under the whole k-loop) ----
    // pack: pos[12:0] | sid[16:13] | mod[18:17] | role[20:19] | pmask[21]
    const int cb = colBase + wc * 64 + (lane & 15);
    float bpv[4];
    #pragma unroll
    for (int n = 0; n < 4; ++n) bpv[n] = bp[s * DMODEL + cb + n * 16];

    int idxv[16];
    u32 metav[16];
    #pragma unroll
    for (int q = 0; q < 16; ++q)
        idxv[q] = eidx[rowBase + wr * 64 + (q >> 2) * 16 + l4 * 4 + (q & 3)];
    #pragma unroll
    for (int q = 0; q < 16; ++q) {
        const int idx = idxv[q];
        metav[q] = (u32)pos[idx]
                 | ((u32)sid[idx] << 13)
                 | ((u32)mod_[idx] << 17)
                 | ((u32)role[idx] << 19)
                 | ((u32)pmask[idx] << 21);
    }

    for (int kk = 0; kk < DIN; kk += 32) {
        // ---- pack current regs -> LDS (proven pack math) ----
        #pragma unroll
        for (int p = 0; p < 4; ++p) {
            const int r = p * 32 + r0;
            const float4 va = rA[p];
            const float4 vb = rB[p];
            uint2 pa, pb;
            pa.x = (__builtin_bit_cast(u32, va.x) >> 16) | (__builtin_bit_cast(u32, va.y) & 0xFFFF0000u);
            pa.y = (__builtin_bit_cast(u32, va.z) >> 16) | (__builtin_bit_cast(u32, va.w) & 0xFFFF0000u);
            pb.x = (__builtin_bit_cast(u32, vb.x) >> 16) | (__builtin_bit_cast(u32, vb.y) & 0xFFFF0000u);
            pb.y = (__builtin_bit_cast(u32, vb.z) >> 16) | (__builtin_bit_cast(u32, vb.w) & 0xFFFF0000u);
            *(uint2*)&Ab[r * LDK32 + c4f] = pa;
            *(uint2*)&Bb[r * LDK32 + c4f] = pb;
        }
        __syncthreads();

        // ---- issue next k-tile loads (hide under MFMA) ----
        if (kk + 32 < DIN) {
            #pragma unroll
            for (int p = 0; p < 4; ++p) {
                const int r = p * 32 + r0;
                rA[p] = *(const float4*)(Ag + (size_t)r * DIN + kk + 32 + c4f);
                rB[p] = *(const float4*)(Bg + (size_t)r * DIN + kk + 32 + c4f);
            }
        }

        // ---- MFMA: one K=32 step (proven fragment pattern) ----
        {
            const int ko = l4 * 8;
            short8 af[4], bf[4];
            #pragma unroll
            for (int m = 0; m < 4; ++m)
                af[m] = *(const short8*)&Ab[(wr * 64 + m * 16 + (lane & 15)) * LDK32 + ko];
            #pragma unroll
            for (int n = 0; n < 4; ++n)
                bf[n] = *(const short8*)&Bb[(wc * 64 + n * 16 + (lane & 15)) * LDK32 + ko];
            #pragma unroll
            for (int m = 0; m < 4; ++m) {
                #pragma unroll
                for (int n = 0; n < 4; ++n)
                    acc[m][n] = __builtin_amdgcn_mfma_f32_16x16x32_bf16(
                        af[m], bf[n], acc[m][n], 0, 0, 0);
            }
        }
        __syncthreads();
    }

    // ---- epilogue: table gathers + stores only (no dependent-load root) ----
    #pragma unroll
    for (int m = 0; m < 4; ++m) {
        #pragma unroll
        for (int j = 0; j < 4; ++j) {
            const int q = m * 4 + j;
            const int idx = idxv[q];
            const u32 mt = metav[q];
            const int p_ = mt & 0x1FFF;
            const int si = (mt >> 13) & 15;
            const int mo = (mt >> 17) & 3;
            const int ro = (mt >> 19) & 3;
            const bool pm = (mt >> 21) & 1;
            const size_t orow =
                ((size_t)(idx >> 12) * LP1 + 1 + (size_t)(idx & 4095)) * DMODEL;
            const float* pr = pos_t + (size_t)p_ * DMODEL;
            const float* ir = id_t + (size_t)si * DMODEL;
            const float* mr = mod_t + (size_t)mo * DMODEL;
            const float* rr = role_t + (size_t)ro * DMODEL;
            #pragma unroll
            for (int n = 0; n < 4; ++n) {
                const int col = cb + n * 16;
                float v = acc[m][n][j] + bpv[n]
                        + pr[col] + ir[col] + mr[col] + rr[col];
                v = pm ? 0.0f : v;
                __builtin_nontemporal_store(v, &out[orow + col]);
            }
        }
    }

    // ---- aux tail (proven): attn_keep + CLS rows ----
    const int gid = bid * 256 + t;
    if (gid < NB * LP1) {
        const size_t OUT_TOK = (size_t)NB * LP1 * DMODEL;
        const int b = gid / LP1;
        const int r = gid - b * LP1;
        float keep = 1.0f;
        if (r > 0) keep = pmask[b * NL + r - 1] ? 0.0f : 1.0f;
        out[OUT_TOK + gid] = keep;
    }
    if (gid < NB * DMODEL) {
        const int b = gid >> 10;
        const int e = gid & (DMODEL - 1);
        out[(size_t)b * LP1 * DMODEL + e] = cls[e];
    }
}

extern "C" void kernel_launch(void* const* d_in, const int* in_sizes, int n_in,
                              void* d_out, int out_size, void* d_ws, size_t ws_size,
                              hipStream_t stream)
{
    (void)in_sizes; (void)n_in; (void)out_size; (void)d_ws; (void)ws_size;
    const float*         emb    = (const float*)d_in[0];
    const int*           eidx   = (const int*)d_in[1];
    const int*           pos    = (const int*)d_in[2];
    const int*           sid    = (const int*)d_in[3];
    const int*           mod_   = (const int*)d_in[4];
    const int*           role   = (const int*)d_in[5];
    const unsigned char* pmask  = (const unsigned char*)d_in[6];
    const float*         Wp     = (const float*)d_in[7];
    const float*         bp     = (const float*)d_in[8];
    const float*         cls    = (const float*)d_in[9];
    const float*         pos_t  = (const float*)d_in[10];
    const float*         id_t   = (const float*)d_in[11];
    const float*         mod_t  = (const float*)d_in[12];
    const float*         role_t = (const float*)d_in[13];
    float* out = (float*)d_out;

    enc_fused<<<4096, 256, 0, stream>>>(emb, eidx, pos, sid, mod_, role, pmask,
                                        Wp, bp, cls, pos_t, id_t, mod_t, role_t, out);
}

// Round 12
// 156.392 us; speedup vs baseline: 1.6125x; 1.6125x over previous
//
#include <hip/hip_runtime.h>
#include <stdint.h>

typedef __attribute__((ext_vector_type(8))) short short8;
typedef __attribute__((ext_vector_type(4))) float f32x4;
typedef unsigned short u16;
typedef unsigned int u32;

#define NSIG   16
#define NPER   4096
#define DIN    256
#define DMODEL 1024
#define NB     16
#define NL     4096
#define LP1    4097
#define LDK32  40   // bf16 row stride: 80B rows -> 16B-aligned b128 reads

// ---------------------------------------------------------------------------
// 512-thread variant of the proven r7 kernel: same 128x128 tile, BK=32,
// but 8 waves -> per-wave 64x32 output, acc[4][2] = 32 AGPRs (was 64).
// Total regs/wave ~80 (was 128) -> 6 waves/SIMD vs 4 -> more TLP for the
// latency-bound gather/scatter epilogue.  All formulas are r7's with
// wc*64 -> wc*32 and n<2.  Epilogue NOT hoisted (r11: cross-loop state
// spills to scratch at this pressure).
// ---------------------------------------------------------------------------
__global__ __launch_bounds__(512, 4)
void enc_fused(const float* __restrict__ emb,     // [65536][256] f32
               const int* __restrict__ eidx,
               const int* __restrict__ pos,
               const int* __restrict__ sid,
               const int* __restrict__ mod_,
               const int* __restrict__ role,
               const unsigned char* __restrict__ pmask,
               const float* __restrict__ Wp,      // [16][1024][256] f32
               const float* __restrict__ bp,
               const float* __restrict__ cls,
               const float* __restrict__ pos_t,
               const float* __restrict__ id_t,
               const float* __restrict__ mod_t,
               const float* __restrict__ role_t,
               float* __restrict__ out)
{
    __shared__ u16 Ab[128 * LDK32];   // 10.0 KB
    __shared__ u16 Bb[128 * LDK32];   // 10.0 KB

    // XCD-chunked bijective swizzle (4096 % 8 == 0)
    const int bid = blockIdx.x;
    const int lg = (bid & 7) * 512 + (bid >> 3);
    const int rowBase = (lg >> 3) * 128;
    const int colBase = (lg & 7) * 128;
    const int s = rowBase >> 12;

    const int t = threadIdx.x;
    const int lane = t & 63;
    const int w = t >> 6;             // 0..7
    const int wr = w >> 2;            // 0..1  (row half: 64 rows)
    const int wc = w & 3;             // 0..3  (col quarter: 32 cols)
    const int l4 = lane >> 4;

    f32x4 acc[4][2] = {};             // 32 AGPRs

    // staging map: 1024 float4-chunks per matrix, 512 threads -> 2 each
    // chunk c: row = c>>3, f32 col = (c&7)*4
    const float* Ag = emb + (size_t)rowBase * DIN;
    const float* Bg = Wp + ((size_t)s * DMODEL + colBase) * DIN;

    // ---- prologue: k-tile 0 into registers ----
    float4 rA[2], rB[2];
    #pragma unroll
    for (int p = 0; p < 2; ++p) {
        const int c = t + 512 * p;
        const int r = c >> 3;
        const int col = (c & 7) * 4;
        rA[p] = *(const float4*)(Ag + (size_t)r * DIN + col);
        rB[p] = *(const float4*)(Bg + (size_t)r * DIN + col);
    }

    for (int kk = 0; kk < DIN; kk += 32) {
        // ---- pack current regs -> LDS (proven pack math) ----
        #pragma unroll
        for (int p = 0; p < 2; ++p) {
            const int c = t + 512 * p;
            const int r = c >> 3;
            const int col = (c & 7) * 4;
            const float4 va = rA[p];
            const float4 vb = rB[p];
            uint2 pa, pb;
            pa.x = (__builtin_bit_cast(u32, va.x) >> 16) | (__builtin_bit_cast(u32, va.y) & 0xFFFF0000u);
            pa.y = (__builtin_bit_cast(u32, va.z) >> 16) | (__builtin_bit_cast(u32, va.w) & 0xFFFF0000u);
            pb.x = (__builtin_bit_cast(u32, vb.x) >> 16) | (__builtin_bit_cast(u32, vb.y) & 0xFFFF0000u);
            pb.y = (__builtin_bit_cast(u32, vb.z) >> 16) | (__builtin_bit_cast(u32, vb.w) & 0xFFFF0000u);
            *(uint2*)&Ab[r * LDK32 + col] = pa;
            *(uint2*)&Bb[r * LDK32 + col] = pb;
        }
        __syncthreads();

        // ---- issue next k-tile loads (hide under MFMA) ----
        if (kk + 32 < DIN) {
            #pragma unroll
            for (int p = 0; p < 2; ++p) {
                const int c = t + 512 * p;
                const int r = c >> 3;
                const int col = (c & 7) * 4;
                rA[p] = *(const float4*)(Ag + (size_t)r * DIN + kk + 32 + col);
                rB[p] = *(const float4*)(Bg + (size_t)r * DIN + kk + 32 + col);
            }
        }

        // ---- MFMA: one K=32 step (proven fragment pattern) ----
        {
            const int ko = l4 * 8;
            short8 af[4], bf[2];
            #pragma unroll
            for (int m = 0; m < 4; ++m)
                af[m] = *(const short8*)&Ab[(wr * 64 + m * 16 + (lane & 15)) * LDK32 + ko];
            #pragma unroll
            for (int n = 0; n < 2; ++n)
                bf[n] = *(const short8*)&Bb[(wc * 32 + n * 16 + (lane & 15)) * LDK32 + ko];
            #pragma unroll
            for (int m = 0; m < 4; ++m) {
                #pragma unroll
                for (int n = 0; n < 2; ++n)
                    acc[m][n] = __builtin_amdgcn_mfma_f32_16x16x32_bf16(
                        af[m], bf[n], acc[m][n], 0, 0, 0);
            }
        }
        __syncthreads();
    }

    // ---- epilogue (r7-style, constants adjusted): bias + gathers + scatter --
    const int cb = colBase + wc * 32 + (lane & 15);
    float bpv[2];
    #pragma unroll
    for (int n = 0; n < 2; ++n) bpv[n] = bp[s * DMODEL + cb + n * 16];

    #pragma unroll
    for (int m = 0; m < 4; ++m) {
        #pragma unroll
        for (int j = 0; j < 4; ++j) {
            const int gr = rowBase + wr * 64 + m * 16 + l4 * 4 + j;
            const int idx = eidx[gr];
            const int p_ = pos[idx];
            const int si = sid[idx];
            const int mo = mod_[idx];
            const int ro = role[idx];
            const int pm = pmask[idx];
            const size_t orow =
                ((size_t)(idx >> 12) * LP1 + 1 + (size_t)(idx & 4095)) * DMODEL;
            #pragma unroll
            for (int n = 0; n < 2; ++n) {
                const int col = cb + n * 16;
                float v = acc[m][n][j] + bpv[n]
                        + pos_t[(size_t)p_ * DMODEL + col]
                        + id_t[si * DMODEL + col]
                        + mod_t[mo * DMODEL + col]
                        + role_t[ro * DMODEL + col];
                v = pm ? 0.0f : v;
                __builtin_nontemporal_store(v, &out[orow + col]);
            }
        }
    }

    // ---- aux tail (proven): attn_keep + CLS rows ----
    const int gid = bid * 512 + t;
    if (gid < NB * LP1) {
        const size_t OUT_TOK = (size_t)NB * LP1 * DMODEL;
        const int b = gid / LP1;
        const int r = gid - b * LP1;
        float keep = 1.0f;
        if (r > 0) keep = pmask[b * NL + r - 1] ? 0.0f : 1.0f;
        out[OUT_TOK + gid] = keep;
    }
    if (gid < NB * DMODEL) {
        const int b = gid >> 10;
        const int e = gid & (DMODEL - 1);
        out[(size_t)b * LP1 * DMODEL + e] = cls[e];
    }
}

extern "C" void kernel_launch(void* const* d_in, const int* in_sizes, int n_in,
                              void* d_out, int out_size, void* d_ws, size_t ws_size,
                              hipStream_t stream)
{
    (void)in_sizes; (void)n_in; (void)out_size; (void)d_ws; (void)ws_size;
    const float*         emb    = (const float*)d_in[0];
    const int*           eidx   = (const int*)d_in[1];
    const int*           pos    = (const int*)d_in[2];
    const int*           sid    = (const int*)d_in[3];
    const int*           mod_   = (const int*)d_in[4];
    const int*           role   = (const int*)d_in[5];
    const unsigned char* pmask  = (const unsigned char*)d_in[6];
    const float*         Wp     = (const float*)d_in[7];
    const float*         bp     = (const float*)d_in[8];
    const float*         cls    = (const float*)d_in[9];
    const float*         pos_t  = (const float*)d_in[10];
    const float*         id_t   = (const float*)d_in[11];
    const float*         mod_t  = (const float*)d_in[12];
    const float*         role_t = (const float*)d_in[13];
    float* out = (float*)d_out;

    enc_fused<<<4096, 512, 0, stream>>>(emb, eidx, pos, sid, mod_, role, pmask,
                                        Wp, bp, cls, pos_t, id_t, mod_t, role_t, out);
}